// Round 1
// baseline (240.879 us; speedup 1.0000x reference)
//
#include <hip/hip_runtime.h>

// UpsampleRFFT = zero-insert 2x upsample + ideal half-band low-pass (circular).
// Closed form: even outputs copy the input exactly; odd outputs are a 128-tap
// circular convolution with g[j] = h[2j+1], h[d] = sign * cot(pi*d/256)/128,
// sign = +1 if d%4==1 else -1. Separable: pass1 along W, pass2 along H.

#define LP   132   // LDS row pitch in floats (132*4B % 16B == 0, breaks bank patterns)
#define NT   512

__global__ __launch_bounds__(NT, 1)
void upsample_rfft_kernel(const float* __restrict__ xin, float* __restrict__ out)
{
    __shared__ __align__(16) float xs[128 * LP];   // input image, row-major
    __shared__ __align__(16) float ts[128 * LP];   // t_odd[r][i] (odd columns of pass1)
    __shared__ float g2[256];                      // taps, duplicated: g2[j] = g[j & 127]

    const int tid = threadIdx.x;
    const long long blk = blockIdx.x;                       // image index (b*64+c)
    const float* __restrict__ xim = xin + blk * (128LL * 128LL);
    float* __restrict__ oim = out + blk * (256LL * 256LL);

    // ---- taps ----
    if (tid < 256) {
        int j = tid & 127;
        int d = 2 * j + 1;                                   // odd lag
        float th = 3.14159265358979323846f * (float)d * (1.0f / 256.0f);
        float s = ((d & 3) == 1) ? 1.0f : -1.0f;
        g2[tid] = s * cosf(th) / (128.0f * sinf(th));
    }

    // ---- load x image (coalesced float4) ----
    {
        const float4* __restrict__ xi4 = (const float4*)xim;
        #pragma unroll
        for (int k = 0; k < 8; ++k) {
            int fidx = k * NT + tid;            // 0..4095 (32 float4 per row)
            int row  = fidx >> 5;
            int c4   = fidx & 31;
            float4 v = xi4[fidx];
            *(float4*)&xs[row * LP + c4 * 4] = v;
        }
    }
    __syncthreads();

    // ---- pass 1 (along W): ts[r][i] = sum_m xs[r][m] * g[(i-m)&127] ----
    {
        const int i0 = (tid & 15) * 8;          // 16 i-tiles of 8
        const int r0 = (tid >> 4) * 4;          // 32 r-tiles of 4
        float acc[4][8];
        #pragma unroll
        for (int q = 0; q < 4; ++q)
            #pragma unroll
            for (int u = 0; u < 8; ++u) acc[q][u] = 0.0f;

        for (int m = 0; m < 128; ++m) {
            float a0 = xs[(r0 + 0) * LP + m];
            float a1 = xs[(r0 + 1) * LP + m];
            float a2 = xs[(r0 + 2) * LP + m];
            float a3 = xs[(r0 + 3) * LP + m];
            int j0 = (i0 - m + 128) & 127;      // g2[j0+u] == g[(i0+u-m)&127]
            float b[8];
            #pragma unroll
            for (int u = 0; u < 8; ++u) b[u] = g2[j0 + u];
            #pragma unroll
            for (int u = 0; u < 8; ++u) {
                acc[0][u] = fmaf(a0, b[u], acc[0][u]);
                acc[1][u] = fmaf(a1, b[u], acc[1][u]);
                acc[2][u] = fmaf(a2, b[u], acc[2][u]);
                acc[3][u] = fmaf(a3, b[u], acc[3][u]);
            }
        }
        #pragma unroll
        for (int q = 0; q < 4; ++q) {
            #pragma unroll
            for (int u = 0; u < 8; u += 4) {
                float4 v = make_float4(acc[q][u], acc[q][u+1], acc[q][u+2], acc[q][u+3]);
                *(float4*)&ts[(r0 + q) * LP + i0 + u] = v;
            }
        }
    }
    __syncthreads();

    // ---- pass 2a: even output rows are copies of t (interleave xs/ts) ----
    {
        #pragma unroll
        for (int k = 0; k < 8; ++k) {
            int gidx = k * NT + tid;            // 0..4095, 8 output cols each
            int row  = gidx >> 5;
            int c0e  = (gidx & 31) * 8;
            float4 vx = *(const float4*)&xs[row * LP + (c0e >> 1)];
            float4 vt = *(const float4*)&ts[row * LP + (c0e >> 1)];
            float4 o0 = make_float4(vx.x, vt.x, vx.y, vt.y);
            float4 o1 = make_float4(vx.z, vt.z, vx.w, vt.w);
            *(float4*)&oim[(2 * row) * 256 + c0e]     = o0;
            *(float4*)&oim[(2 * row) * 256 + c0e + 4] = o1;
        }
    }

    // ---- pass 2b: odd output rows: out[2p+1][c] = sum_m t[m][c]*g[(p-m)&127] ----
    {
        const int c0 = (tid & 31) * 8;          // 32 c-tiles of 8
        const int p0 = (tid >> 5) * 8;          // 16 p-tiles of 8
        float acc[8][8];
        #pragma unroll
        for (int v = 0; v < 8; ++v)
            #pragma unroll
            for (int u = 0; u < 8; ++u) acc[v][u] = 0.0f;

        for (int m = 0; m < 128; ++m) {
            int j1 = (p0 - m + 128) & 127;
            float ga[8];
            #pragma unroll
            for (int v = 0; v < 8; ++v) ga[v] = g2[j1 + v];
            float4 bx = *(const float4*)&xs[m * LP + (c0 >> 1)];  // even cols of t
            float4 bt = *(const float4*)&ts[m * LP + (c0 >> 1)];  // odd  cols of t
            #pragma unroll
            for (int v = 0; v < 8; ++v) {
                acc[v][0] = fmaf(ga[v], bx.x, acc[v][0]);
                acc[v][1] = fmaf(ga[v], bt.x, acc[v][1]);
                acc[v][2] = fmaf(ga[v], bx.y, acc[v][2]);
                acc[v][3] = fmaf(ga[v], bt.y, acc[v][3]);
                acc[v][4] = fmaf(ga[v], bx.z, acc[v][4]);
                acc[v][5] = fmaf(ga[v], bt.z, acc[v][5]);
                acc[v][6] = fmaf(ga[v], bx.w, acc[v][6]);
                acc[v][7] = fmaf(ga[v], bt.w, acc[v][7]);
            }
        }
        #pragma unroll
        for (int v = 0; v < 8; ++v) {
            float4 o0 = make_float4(acc[v][0], acc[v][1], acc[v][2], acc[v][3]);
            float4 o1 = make_float4(acc[v][4], acc[v][5], acc[v][6], acc[v][7]);
            float* orow = &oim[(2 * (p0 + v) + 1) * 256 + c0];
            *(float4*)&orow[0] = o0;
            *(float4*)&orow[4] = o1;
        }
    }
}

extern "C" void kernel_launch(void* const* d_in, const int* in_sizes, int n_in,
                              void* d_out, int out_size, void* d_ws, size_t ws_size,
                              hipStream_t stream)
{
    (void)n_in; (void)d_out; (void)out_size; (void)d_ws; (void)ws_size;
    const float* x = (const float*)d_in[0];
    float* out = (float*)d_out;
    int nimg = in_sizes[0] / (128 * 128);       // 16*64 = 1024 images
    hipLaunchKernelGGL(upsample_rfft_kernel, dim3(nimg), dim3(NT), 0, stream, x, out);
}